// Round 3
// baseline (3037.082 us; speedup 1.0000x reference)
//
#include <hip/hip_runtime.h>
#include <hip/hip_bf16.h>

// Problem constants: B=2, C=64, H=48, W=64, D=49, BD=98. All I/O fp32.
// conv0: 128->96 (feat1 half precomputed as part0), conv1: 96->128 s2,
// conv2: 128->128, conv3: 128->64, deconv k4s2: 64->32, conv5: 32->1,
// DAP 49x49, softmax flow regression.
// Pipeline chunked over the 98 (b,displacement) images; chunk size chosen
// from ws_size on the host (constant across calls -> graph-capture safe).

// ---------------------------------------------------------------------------
__global__ void sentinel_k(float* __restrict__ out, int nel, float val) {
    int i = blockIdx.x * 256 + threadIdx.x;
    if (i < nel) out[i] = val;
}

// ---------------------------------------------------------------------------
// part0 = b0 + conv3x3(feat1, w0[:, 0:64])   -> (2, 96, 48, 64) fp32
// ---------------------------------------------------------------------------
__global__ void part0_kernel(const float* __restrict__ feat1, const float* __restrict__ w0,
                             const float* __restrict__ b0, float* __restrict__ part0) {
    int idx = blockIdx.x * 256 + threadIdx.x;
    if (idx >= 2 * 96 * 48 * 64) return;
    int x = idx & 63;
    int y = (idx >> 6) % 48;
    int oc = (idx / 3072) % 96;
    int b = idx / (3072 * 96);
    float acc = b0[oc];
    const float* f1 = feat1 + (size_t)b * 64 * 3072;
    const float* w = w0 + (size_t)oc * 128 * 9;  // ic 0..63 of 128
    for (int ic = 0; ic < 64; ++ic) {
        const float* fc = f1 + ic * 3072;
        const float* wc = w + ic * 9;
#pragma unroll
        for (int ky = 0; ky < 3; ++ky) {
            int yy = y + ky - 1;
            if (yy < 0 || yy >= 48) continue;
#pragma unroll
            for (int kx = 0; kx < 3; ++kx) {
                int xx = x + kx - 1;
                if (xx < 0 || xx >= 64) continue;
                acc = fmaf(fc[yy * 64 + xx], wc[ky * 3 + kx], acc);
            }
        }
    }
    part0[idx] = acc;
}

// ---------------------------------------------------------------------------
// warp: bilinear sample feat2 at coords + (du,dv); chunk of cnt images
// writes f2w local (cnt, 64, 48, 64) fp32; global bd = bd0 + z
// ---------------------------------------------------------------------------
__global__ void warp_kernel(const float* __restrict__ feat2, const float* __restrict__ coords,
                            float* __restrict__ f2w, int bd0, int cnt) {
    int idx = blockIdx.x * 256 + threadIdx.x;
    if (idx >= cnt * 3072) return;
    int p = idx % 3072;
    int z = idx / 3072;
    int bd = bd0 + z;
    int b = bd / 49;
    int d = bd % 49;
    float du = (float)(d % 7 - 3), dv = (float)(d / 7 - 3);
    float cx = coords[(size_t)(b * 2 + 0) * 3072 + p] + du;
    float cy = coords[(size_t)(b * 2 + 1) * 3072 + p] + dv;
    float x0f = floorf(cx), y0f = floorf(cy);
    float wx = cx - x0f, wy = cy - y0f;
    int x0 = (int)x0f, y0 = (int)y0f;
    int x1 = x0 + 1, y1 = y0 + 1;
    bool vx0 = (x0 >= 0) && (x0 < 64), vx1 = (x1 >= 0) && (x1 < 64);
    bool vy0 = (y0 >= 0) && (y0 < 48), vy1 = (y1 >= 0) && (y1 < 48);
    int xc0 = min(max(x0, 0), 63), xc1 = min(max(x1, 0), 63);
    int yc0 = min(max(y0, 0), 47), yc1 = min(max(y1, 0), 47);
    int i00 = yc0 * 64 + xc0, i01 = yc0 * 64 + xc1;
    int i10 = yc1 * 64 + xc0, i11 = yc1 * 64 + xc1;
    float w00 = (vx0 && vy0) ? (1.f - wx) * (1.f - wy) : 0.f;
    float w01 = (vx1 && vy0) ? wx * (1.f - wy) : 0.f;
    float w10 = (vx0 && vy1) ? (1.f - wx) * wy : 0.f;
    float w11 = (vx1 && vy1) ? wx * wy : 0.f;
    const float* f2 = feat2 + (size_t)b * 64 * 3072;
    float* out = f2w + (size_t)z * 64 * 3072 + p;
    for (int c = 0; c < 64; ++c) {
        const float* fc = f2 + c * 3072;
        float v = w00 * fc[i00] + w01 * fc[i01] + w10 * fc[i10] + w11 * fc[i11];
        out[(size_t)c * 3072] = v;
    }
}

// ---------------------------------------------------------------------------
// Generic 3x3 stride-1 conv, ReLU. Each thread: 4 px (x) x 16 oc.
// HAS_BASE: adds fp32 base map part0[(b,oc,y,x)] (bias folded), b from bd0+z.
// Else adds bias[oc]. Buffers indexed by local z = blockIdx.z.
// ---------------------------------------------------------------------------
template <int IC, int WIC, int ICB, int OC_TOTAL, int HH, int WW, bool HAS_BASE>
__global__ __launch_bounds__(256) void conv3x3_s1(const float* __restrict__ in,
                                                  const float* __restrict__ wgt,
                                                  const float* __restrict__ bias,
                                                  const float* __restrict__ base,
                                                  float* __restrict__ out, int bd0) {
    constexpr int OCT = 16;
    constexpr int ICC = 8;
    constexpr int TCOLS = WW / 4;
    constexpr int TROWS = 256 / TCOLS;
    constexpr int PITCH = ((WW + 2 + 3) / 4) * 4;
    __shared__ __align__(16) float s_in[ICC][TROWS + 2][PITCH];
    __shared__ __align__(16) float s_w[ICC * 9 * OCT];

    const int tid = threadIdx.x;
    const int ty = tid / TCOLS, tx = tid % TCOLS;
    const int y0 = blockIdx.x * TROWS;
    const int ocg = blockIdx.y;
    const int z = blockIdx.z;
    const int oy = y0 + ty;
    const int ox0 = tx * 4;

    float acc[4][OCT];
#pragma unroll
    for (int i = 0; i < 4; ++i)
#pragma unroll
        for (int j = 0; j < OCT; ++j) acc[i][j] = 0.f;

    for (int cc = 0; cc < IC / ICC; ++cc) {
        constexpr int IN_ELEMS = ICC * (TROWS + 2) * (WW + 2);
        for (int i = tid; i < IN_ELEMS; i += 256) {
            int c = i % (WW + 2);
            int r = (i / (WW + 2)) % (TROWS + 2);
            int ic = i / ((WW + 2) * (TROWS + 2));
            int gy = y0 + r - 1, gx = c - 1;
            float v = 0.f;
            if (gy >= 0 && gy < HH && gx >= 0 && gx < WW)
                v = in[((size_t)z * IC + cc * ICC + ic) * (HH * WW) + gy * WW + gx];
            s_in[ic][r][c] = v;
        }
        for (int i = tid; i < ICC * 9 * OCT; i += 256) {
            int oc = i % OCT;
            int k = (i / OCT) % 9;
            int ic = i / (OCT * 9);
            s_w[(ic * 9 + k) * OCT + oc] =
                wgt[((size_t)(ocg * OCT + oc) * WIC + ICB + cc * ICC + ic) * 9 + k];
        }
        __syncthreads();
        if (oy < HH) {
            for (int ic = 0; ic < ICC; ++ic) {
#pragma unroll
                for (int ky = 0; ky < 3; ++ky) {
                    const float* row = &s_in[ic][ty + ky][ox0];
                    float4 a03 = *(const float4*)row;
                    float2 a45 = *(const float2*)(row + 4);
                    float av[6] = {a03.x, a03.y, a03.z, a03.w, a45.x, a45.y};
#pragma unroll
                    for (int kx = 0; kx < 3; ++kx) {
                        const float4* wp = (const float4*)&s_w[(ic * 9 + ky * 3 + kx) * OCT];
                        float4 w0v = wp[0], w1v = wp[1], w2v = wp[2], w3v = wp[3];
                        float wv[16] = {w0v.x, w0v.y, w0v.z, w0v.w, w1v.x, w1v.y, w1v.z, w1v.w,
                                        w2v.x, w2v.y, w2v.z, w2v.w, w3v.x, w3v.y, w3v.z, w3v.w};
#pragma unroll
                        for (int oc = 0; oc < OCT; ++oc) {
#pragma unroll
                            for (int px = 0; px < 4; ++px)
                                acc[px][oc] = fmaf(av[px + kx], wv[oc], acc[px][oc]);
                        }
                    }
                }
            }
        }
        __syncthreads();
    }

    if (oy < HH) {
        const int b = (bd0 + z) / 49;
#pragma unroll
        for (int oc = 0; oc < OCT; ++oc) {
            const int oco = ocg * OCT + oc;
            float bb = 0.f;
            if constexpr (!HAS_BASE) bb = bias[oco];
#pragma unroll
            for (int px = 0; px < 4; ++px) {
                float v = acc[px][oc];
                if constexpr (HAS_BASE)
                    v += base[((size_t)(b * OC_TOTAL + oco)) * (HH * WW) + oy * WW + ox0 + px];
                else
                    v += bb;
                v = fmaxf(v, 0.f);
                out[((size_t)z * OC_TOTAL + oco) * (HH * WW) + oy * WW + ox0 + px] = v;
            }
        }
    }
}

// ---------------------------------------------------------------------------
// conv1: 3x3 stride-2 pad-1, 96->128, ReLU. (z,96,48,64) -> (z,128,24,32)
// ---------------------------------------------------------------------------
__global__ __launch_bounds__(256) void conv1_s2(const float* __restrict__ in,
                                                const float* __restrict__ wgt,
                                                const float* __restrict__ bias,
                                                float* __restrict__ out) {
    constexpr int ICC = 4;
    __shared__ __align__(16) float s_in[ICC][33][68];
    __shared__ __align__(16) float s_w[ICC * 9 * 16];
    const int tid = threadIdx.x;
    const int ty = tid / 16, tx = tid % 16;
    const int y0 = blockIdx.x * 16;
    const int ocg = blockIdx.y;
    const int z = blockIdx.z;
    const int oy = y0 + ty;

    float acc[2][16];
#pragma unroll
    for (int i = 0; i < 2; ++i)
#pragma unroll
        for (int j = 0; j < 16; ++j) acc[i][j] = 0.f;

    for (int cc = 0; cc < 96 / ICC; ++cc) {
        const int IN_ELEMS = ICC * 33 * 65;
        for (int i = tid; i < IN_ELEMS; i += 256) {
            int c = i % 65;
            int r = (i / 65) % 33;
            int ic = i / (65 * 33);
            int gy = 2 * y0 - 1 + r, gx = c - 1;
            float v = 0.f;
            if (gy >= 0 && gy < 48 && gx >= 0 && gx < 64)
                v = in[((size_t)z * 96 + cc * ICC + ic) * 3072 + gy * 64 + gx];
            s_in[ic][r][c] = v;
        }
        for (int i = tid; i < ICC * 9 * 16; i += 256) {
            int oc = i % 16;
            int k = (i / 16) % 9;
            int ic = i / (16 * 9);
            s_w[(ic * 9 + k) * 16 + oc] =
                wgt[((size_t)(ocg * 16 + oc) * 96 + cc * ICC + ic) * 9 + k];
        }
        __syncthreads();
        if (oy < 24) {
            for (int ic = 0; ic < ICC; ++ic) {
#pragma unroll
                for (int ky = 0; ky < 3; ++ky) {
                    const float* row = &s_in[ic][2 * ty + ky][4 * tx];
                    float4 a03 = *(const float4*)row;
                    float a4 = row[4];
                    float av[5] = {a03.x, a03.y, a03.z, a03.w, a4};
#pragma unroll
                    for (int kx = 0; kx < 3; ++kx) {
                        const float4* wp = (const float4*)&s_w[(ic * 9 + ky * 3 + kx) * 16];
                        float4 w0v = wp[0], w1v = wp[1], w2v = wp[2], w3v = wp[3];
                        float wv[16] = {w0v.x, w0v.y, w0v.z, w0v.w, w1v.x, w1v.y, w1v.z, w1v.w,
                                        w2v.x, w2v.y, w2v.z, w2v.w, w3v.x, w3v.y, w3v.z, w3v.w};
#pragma unroll
                        for (int oc = 0; oc < 16; ++oc) {
                            acc[0][oc] = fmaf(av[kx], wv[oc], acc[0][oc]);
                            acc[1][oc] = fmaf(av[kx + 2], wv[oc], acc[1][oc]);
                        }
                    }
                }
            }
        }
        __syncthreads();
    }
    if (oy < 24) {
#pragma unroll
        for (int oc = 0; oc < 16; ++oc) {
            int oco = ocg * 16 + oc;
            float bb = bias[oco];
#pragma unroll
            for (int px = 0; px < 2; ++px) {
                float v = fmaxf(acc[px][oc] + bb, 0.f);
                out[((size_t)z * 128 + oco) * 768 + oy * 32 + tx * 2 + px] = v;
            }
        }
    }
}

// ---------------------------------------------------------------------------
// deconv: transposed conv k=4 s=2 p=1 (JAX correlation, no kernel flip),
// 64->32, ReLU. (z,64,24,32)->(z,32,48,64)
// ---------------------------------------------------------------------------
__global__ __launch_bounds__(256) void deconv_k(const float* __restrict__ in,
                                                const float* __restrict__ wgt,
                                                const float* __restrict__ bias,
                                                float* __restrict__ out) {
    constexpr int ICC = 8;
    __shared__ __align__(16) float s_in[ICC][10][36];
    __shared__ __align__(16) float s_w[ICC * 16 * 16];
    const int tid = threadIdx.x;
    const int ty = tid / 16, tx = tid % 16;
    const int y0 = blockIdx.x * 16;  // even
    const int ocg = blockIdx.y;      // 2 groups
    const int z = blockIdx.z;
    const int oy = y0 + ty;
    const int par = ty & 1;

    float acc[4][16];
#pragma unroll
    for (int i = 0; i < 4; ++i)
#pragma unroll
        for (int j = 0; j < 16; ++j) acc[i][j] = 0.f;

    for (int cc = 0; cc < 8; ++cc) {
        const int IN_ELEMS = ICC * 10 * 34;
        for (int i = tid; i < IN_ELEMS; i += 256) {
            int c = i % 34;
            int r = (i / 34) % 10;
            int ic = i / 340;
            int gy = y0 / 2 - 1 + r, gx = c - 1;
            float v = 0.f;
            if (gy >= 0 && gy < 24 && gx >= 0 && gx < 32)
                v = in[((size_t)z * 64 + cc * 8 + ic) * 768 + gy * 32 + gx];
            s_in[ic][r][c] = v;
        }
        for (int i = tid; i < ICC * 16 * 16; i += 256) {
            int oc = i % 16;
            int k = (i / 16) % 16;
            int ic = i / 256;
            s_w[(ic * 16 + k) * 16 + oc] =
                wgt[((size_t)(ocg * 16 + oc) * 64 + cc * 8 + ic) * 16 + k];
        }
        __syncthreads();
        for (int ic = 0; ic < 8; ++ic) {
#pragma unroll
            for (int ky2 = 0; ky2 < 2; ++ky2) {
                const int ky = par + 2 * ky2;
                const float* row = &s_in[ic][(ty + ky - 2) / 2 + 1][2 * tx];
#pragma unroll
                for (int kx = 0; kx < 4; ++kx) {
                    const int p0 = kx & 1;
                    const int off = (p0 + kx) >> 1;
                    float a0 = row[off], a1 = row[off + 1];
                    const float4* wp = (const float4*)&s_w[(ic * 16 + ky * 4 + kx) * 16];
                    float4 w0v = wp[0], w1v = wp[1], w2v = wp[2], w3v = wp[3];
                    float wv[16] = {w0v.x, w0v.y, w0v.z, w0v.w, w1v.x, w1v.y, w1v.z, w1v.w,
                                    w2v.x, w2v.y, w2v.z, w2v.w, w3v.x, w3v.y, w3v.z, w3v.w};
#pragma unroll
                    for (int oc = 0; oc < 16; ++oc) {
                        acc[p0][oc] = fmaf(a0, wv[oc], acc[p0][oc]);
                        acc[p0 + 2][oc] = fmaf(a1, wv[oc], acc[p0 + 2][oc]);
                    }
                }
            }
        }
        __syncthreads();
    }
#pragma unroll
    for (int oc = 0; oc < 16; ++oc) {
        int oco = ocg * 16 + oc;
        float bb = bias[oco];
#pragma unroll
        for (int px = 0; px < 4; ++px) {
            float v = fmaxf(acc[px][oc] + bb, 0.f);
            out[((size_t)z * 32 + oco) * 3072 + oy * 64 + tx * 4 + px] = v;
        }
    }
}

// ---------------------------------------------------------------------------
// conv5: 3x3, 32->1, no ReLU. (z,32,48,64) -> cost[(bd0+z), 3072] fp32
// ---------------------------------------------------------------------------
__global__ __launch_bounds__(256) void conv5_k(const float* __restrict__ in,
                                               const float* __restrict__ w5,
                                               const float* __restrict__ b5,
                                               float* __restrict__ cost, int bd0) {
    constexpr int ICC = 8;
    __shared__ __align__(16) float s_in[ICC][18][68];
    __shared__ __align__(16) float s_w[32 * 9];
    const int tid = threadIdx.x;
    const int ty = tid / 16, tx = tid % 16;
    const int y0 = blockIdx.x * 16;
    const int z = blockIdx.y;
    const int oy = y0 + ty;
    for (int i = tid; i < 288; i += 256) s_w[i] = w5[i];
    float acc[4] = {0.f, 0.f, 0.f, 0.f};
    for (int cc = 0; cc < 4; ++cc) {
        const int IN_ELEMS = ICC * 18 * 66;
        for (int i = tid; i < IN_ELEMS; i += 256) {
            int c = i % 66;
            int r = (i / 66) % 18;
            int ic = i / (66 * 18);
            int gy = y0 + r - 1, gx = c - 1;
            float v = 0.f;
            if (gy >= 0 && gy < 48 && gx >= 0 && gx < 64)
                v = in[((size_t)z * 32 + cc * 8 + ic) * 3072 + gy * 64 + gx];
            s_in[ic][r][c] = v;
        }
        __syncthreads();
        for (int ic = 0; ic < 8; ++ic) {
#pragma unroll
            for (int ky = 0; ky < 3; ++ky) {
                const float* row = &s_in[ic][ty + ky][tx * 4];
                float4 a03 = *(const float4*)row;
                float2 a45 = *(const float2*)(row + 4);
                float av[6] = {a03.x, a03.y, a03.z, a03.w, a45.x, a45.y};
#pragma unroll
                for (int kx = 0; kx < 3; ++kx) {
                    float wv = s_w[(cc * 8 + ic) * 9 + ky * 3 + kx];
#pragma unroll
                    for (int px = 0; px < 4; ++px) acc[px] = fmaf(av[px + kx], wv, acc[px]);
                }
            }
        }
        __syncthreads();
    }
    float bb = b5[0];
#pragma unroll
    for (int px = 0; px < 4; ++px)
        cost[(size_t)(bd0 + z) * 3072 + oy * 64 + tx * 4 + px] = acc[px] + bb;
}

// ---------------------------------------------------------------------------
// DAP (49x49 1x1) + softmax + flow expectation + add coords. out fp32 (2,2,48,64)
// Sentinel 3000 if cost has NaN/huge values (upstream garbage detector).
// ---------------------------------------------------------------------------
__global__ __launch_bounds__(256) void dap_flow(const float* __restrict__ cost,
                                                const float* __restrict__ wdap,
                                                const float* __restrict__ coords,
                                                float* __restrict__ outp) {
    __shared__ float s_w[49 * 49];
    int tid = threadIdx.x;
    for (int i = tid; i < 2401; i += 256) s_w[i] = wdap[i];
    __syncthreads();
    int idx = blockIdx.x * 256 + tid;
    if (idx >= 2 * 3072) return;
    int p = idx % 3072, b = idx / 3072;
    float c[49];
    bool bad = false;
#pragma unroll
    for (int d = 0; d < 49; ++d) {
        c[d] = cost[((size_t)(b * 49 + d)) * 3072 + p];
        if (!(fabsf(c[d]) <= 1e20f)) bad = true;  // catches NaN and Inf/huge
    }
    float m = -1e30f;
    for (int e = 0; e < 49; ++e) {
        float s = 0.f;
#pragma unroll
        for (int d = 0; d < 49; ++d) s = fmaf(s_w[e * 49 + d], c[d], s);
        m = fmaxf(m, s);
    }
    float sum = 0.f, sx = 0.f, sy = 0.f;
    for (int e = 0; e < 49; ++e) {
        float s = 0.f;
#pragma unroll
        for (int d = 0; d < 49; ++d) s = fmaf(s_w[e * 49 + d], c[d], s);
        float pr = __expf(s - m);
        sum += pr;
        sx += pr * (float)(e % 7 - 3);
        sy += pr * (float)(e / 7 - 3);
    }
    float inv = 1.f / sum;
    float o0 = coords[(size_t)(b * 2 + 0) * 3072 + p] + sx * inv;
    float o1 = coords[(size_t)(b * 2 + 1) * 3072 + p] + sy * inv;
    if (bad) { o0 = 3000.f; o1 = 3000.f; }
    outp[(size_t)(b * 2 + 0) * 3072 + p] = o0;
    outp[(size_t)(b * 2 + 1) * 3072 + p] = o1;
}

// ---------------------------------------------------------------------------
extern "C" void kernel_launch(void* const* d_in, const int* in_sizes, int n_in,
                              void* d_out, int out_size, void* d_ws, size_t ws_size,
                              hipStream_t stream) {
    (void)in_sizes; (void)n_in;
    const float* feat1 = (const float*)d_in[0];
    const float* feat2 = (const float*)d_in[1];
    const float* coords = (const float*)d_in[2];
    const float* w0 = (const float*)d_in[3];
    const float* b0 = (const float*)d_in[4];
    const float* w1 = (const float*)d_in[5];
    const float* b1 = (const float*)d_in[6];
    const float* w2 = (const float*)d_in[7];
    const float* b2 = (const float*)d_in[8];
    const float* w3 = (const float*)d_in[9];
    const float* b3 = (const float*)d_in[10];
    const float* wd = (const float*)d_in[11];
    const float* bdc = (const float*)d_in[12];
    const float* w5 = (const float*)d_in[13];
    const float* b5 = (const float*)d_in[14];
    const float* wdap = (const float*)d_in[15];
    float* outp = (float*)d_out;

    // Workspace layout (chunked over the 98 bd-images, chunk size n), fp32:
    //   part0: fp32 (2,96,48,64)                        2,359,296 B
    //   A: max(f2w, x1, x3) = 786,432*n B   (f2w fp32 (n,64,48,64))
    //   B: max(x0, x2, xd) = 1,179,648*n B  (x0 fp32 (n,96,48,64))
    //   cost: fp32 (98,3072)                            1,204,224 B
    // need(n) = 3,563,520 + 1,966,080*n
    const size_t base_need = 2359296 + 1204224;
    const int cand[7] = {98, 49, 25, 14, 7, 2, 1};
    int n = 0;
    for (int i = 0; i < 7; ++i) {
        if (base_need + (size_t)1966080 * cand[i] <= ws_size) { n = cand[i]; break; }
    }
    if (n == 0) {
        // workspace too small — emit distinctive sentinel (10000 + MB)
        float val = 10000.f + (float)(ws_size >> 20);
        sentinel_k<<<dim3((out_size + 255) / 256), 256, 0, stream>>>(outp, out_size, val);
        return;
    }

    char* ws = (char*)d_ws;
    float* part0 = (float*)(ws + 0);
    char* regA = ws + 2359296;
    char* regB = regA + (size_t)786432 * n;
    float* cost = (float*)(regB + (size_t)1179648 * n);

    float* f2w = (float*)regA;
    float* x1 = (float*)regA;   // reuse A after conv0 consumes f2w
    float* x3 = (float*)regA;   // reuse A after conv2 consumes x1
    float* x0 = (float*)regB;
    float* x2 = (float*)regB;   // reuse B after conv1 consumes x0
    float* xd = (float*)regB;   // reuse B after conv3 consumes x2

    part0_kernel<<<dim3(2304), 256, 0, stream>>>(feat1, w0, b0, part0);

    for (int s = 0; s < 98; s += n) {
        int cnt = (98 - s < n) ? (98 - s) : n;
        warp_kernel<<<dim3((cnt * 3072 + 255) / 256), 256, 0, stream>>>(feat2, coords, f2w, s, cnt);
        // conv0: f2-half + part0, ReLU -> x0 (cnt,96,48,64)
        conv3x3_s1<64, 128, 64, 96, 48, 64, true>
            <<<dim3(3, 6, cnt), 256, 0, stream>>>(f2w, w0, nullptr, part0, x0, s);
        // conv1 s2 -> x1 (cnt,128,24,32)
        conv1_s2<<<dim3(2, 8, cnt), 256, 0, stream>>>(x0, w1, b1, x1);
        // conv2 -> x2 (cnt,128,24,32)
        conv3x3_s1<128, 128, 0, 128, 24, 32, false>
            <<<dim3(1, 8, cnt), 256, 0, stream>>>(x1, w2, b2, nullptr, x2, 0);
        // conv3 -> x3 (cnt,64,24,32)
        conv3x3_s1<128, 128, 0, 64, 24, 32, false>
            <<<dim3(1, 4, cnt), 256, 0, stream>>>(x2, w3, b3, nullptr, x3, 0);
        // deconv -> xd (cnt,32,48,64)
        deconv_k<<<dim3(3, 2, cnt), 256, 0, stream>>>(x3, wd, bdc, xd);
        // conv5 -> cost (98,3072) fp32 at global bd offset
        conv5_k<<<dim3(3, cnt), 256, 0, stream>>>(xd, w5, b5, cost, s);
    }

    // DAP + softmax + flow -> out (2,2,48,64) fp32
    dap_flow<<<dim3(24), 256, 0, stream>>>(cost, wdap, coords, outp);
}

// Round 4
// 1597.719 us; speedup vs baseline: 1.9009x; 1.9009x over previous
//
#include <hip/hip_runtime.h>
#include <hip/hip_bf16.h>

using bf16 = __hip_bfloat16;
typedef __attribute__((ext_vector_type(8))) __bf16 bf16x8;
typedef __attribute__((ext_vector_type(4))) float f32x4;

static __device__ __forceinline__ bf16 f2b(float v) { return __float2bfloat16(v); }
static __device__ __forceinline__ float us2f(unsigned short u) {
    return __uint_as_float(((unsigned)u) << 16);
}

// Problem: B=2, C=64, H=48, W=64, D=49, BD=98. fp32 I/O.
// MFMA pipeline, NHWC bf16 intermediates:
//  part0 (scalar fp32): b0 + conv(feat1, w0[:, :64])        -> (2,48,64,96) NHWC fp32
//  warp  -> f2w (nb,48,64,64) NHWC bf16
//  conv0 (MFMA, +part0 base, ReLU) -> x0p parity-packed (nb,24,32,384)
//  conv1 = dense conv over parity planes (IC=384, taps{-1,0}^2) -> x1 (nb,24,32,128)
//  conv2 -> x2 (nb,24,32,128); conv3 -> x3 (nb,24,32,64)
//  deconv = 4 parity-class 2x2-tap convs -> xd (nb,48,64,32)
//  conv5 (scalar) -> cost (98,3072) fp32;  dap_flow -> out

// ---------------------------------------------------------------------------
__global__ void sentinel_k(float* __restrict__ out, int nel, float val) {
    int i = blockIdx.x * 256 + threadIdx.x;
    if (i < nel) out[i] = val;
}

// ---------------------------------------------------------------------------
// Weight packing: wp[t][oc][ic] bf16
// ---------------------------------------------------------------------------
__global__ void pack_w0(const float* __restrict__ w0, bf16* __restrict__ wp) {
    int i = blockIdx.x * 256 + threadIdx.x;
    if (i >= 9 * 96 * 64) return;
    int ic = i % 64, oc = (i / 64) % 96, t = i / (64 * 96);
    wp[i] = f2b(w0[((size_t)oc * 128 + 64 + ic) * 9 + t]);
}

__global__ void pack_simple(const float* __restrict__ w, bf16* __restrict__ wp,
                            int OC, int IC, int T) {
    int i = blockIdx.x * 256 + threadIdx.x;
    if (i >= T * OC * IC) return;
    int ic = i % IC, oc = (i / IC) % OC, t = i / (IC * OC);
    wp[i] = f2b(w[((size_t)oc * IC + ic) * T + t]);
}

// conv1 parity-plane weights: wp1[t2][128][384], t2=(dy+1)*2+(dx+1), dy,dx in {-1,0}
// channel pc = (py*2+px)*96+ic matching x0p layout.
__global__ void pack_w1(const float* __restrict__ w1, bf16* __restrict__ wp) {
    int i = blockIdx.x * 256 + threadIdx.x;
    if (i >= 4 * 128 * 384) return;
    int pc = i % 384, oc = (i / 384) % 128, t2 = i / (384 * 128);
    int dy = (t2 < 2) ? -1 : 0;
    int dx = (t2 & 1) ? 0 : -1;
    int p = pc / 96, ic = pc % 96;
    int py = p >> 1, px = p & 1;
    int ky = (dy == -1) ? (py == 1 ? 0 : -1) : (py == 0 ? 1 : 2);
    int kx = (dx == -1) ? (px == 1 ? 0 : -1) : (px == 0 ? 1 : 2);
    float v = (ky >= 0 && kx >= 0) ? w1[((size_t)oc * 96 + ic) * 9 + ky * 3 + kx] : 0.f;
    wp[i] = f2b(v);
}

// deconv class weights: wpd[c][t2][32][64], c=qy*2+qx, dy=qy-1+t2/2, dx=qx-1+t2%2
__global__ void pack_wd(const float* __restrict__ wd, bf16* __restrict__ wp) {
    int i = blockIdx.x * 256 + threadIdx.x;
    if (i >= 4 * 4 * 32 * 64) return;
    int ic = i % 64, oc = (i / 64) % 32, t2 = (i / 2048) % 4, c = i / 8192;
    int qy = c >> 1, qx = c & 1;
    int dy = qy - 1 + (t2 >> 1), dx = qx - 1 + (t2 & 1);
    int ky = (qy == 0) ? (dy == -1 ? 0 : 2) : (dy == 0 ? 1 : 3);
    int kx = (qx == 0) ? (dx == -1 ? 0 : 2) : (dx == 0 ? 1 : 3);
    wp[i] = f2b(wd[((size_t)oc * 64 + ic) * 16 + ky * 4 + kx]);
}

// ---------------------------------------------------------------------------
// part0 = b0 + conv3x3(feat1, w0[:, :64]) -> NHWC fp32 (2,48,64,96)
// ---------------------------------------------------------------------------
__global__ void part0_kernel(const float* __restrict__ feat1, const float* __restrict__ w0,
                             const float* __restrict__ b0, float* __restrict__ part0) {
    int i = blockIdx.x * 256 + threadIdx.x;
    if (i >= 2 * 48 * 64 * 96) return;
    int oc = i % 96;
    int x = (i / 96) % 64;
    int y = (i / (96 * 64)) % 48;
    int b = i / (96 * 64 * 48);
    float acc = b0[oc];
    const float* f1 = feat1 + (size_t)b * 64 * 3072;
    const float* w = w0 + (size_t)oc * 128 * 9;  // ic 0..63 of 128
    for (int ic = 0; ic < 64; ++ic) {
        const float* fc = f1 + ic * 3072;
        const float* wc = w + ic * 9;
#pragma unroll
        for (int ky = 0; ky < 3; ++ky) {
            int yy = y + ky - 1;
            if (yy < 0 || yy >= 48) continue;
#pragma unroll
            for (int kx = 0; kx < 3; ++kx) {
                int xx = x + kx - 1;
                if (xx < 0 || xx >= 64) continue;
                acc = fmaf(fc[yy * 64 + xx], wc[ky * 3 + kx], acc);
            }
        }
    }
    part0[i] = acc;
}

// ---------------------------------------------------------------------------
// warp: one wave per pixel, lane = channel. out NHWC bf16 (cnt,48,64,64)
// ---------------------------------------------------------------------------
__global__ void warp_kernel(const float* __restrict__ feat2, const float* __restrict__ coords,
                            bf16* __restrict__ f2w, int bd0, int cnt) {
    int pix = blockIdx.x * 4 + (threadIdx.x >> 6);
    int c = threadIdx.x & 63;
    if (pix >= cnt * 3072) return;
    int p = pix % 3072;
    int z = pix / 3072;
    int bd = bd0 + z;
    int b = bd / 49, d = bd % 49;
    float du = (float)(d % 7 - 3), dv = (float)(d / 7 - 3);
    float cx = coords[(size_t)(b * 2 + 0) * 3072 + p] + du;
    float cy = coords[(size_t)(b * 2 + 1) * 3072 + p] + dv;
    float x0f = floorf(cx), y0f = floorf(cy);
    float wx = cx - x0f, wy = cy - y0f;
    int x0 = (int)x0f, y0 = (int)y0f;
    int x1 = x0 + 1, y1 = y0 + 1;
    bool vx0 = (x0 >= 0) && (x0 < 64), vx1 = (x1 >= 0) && (x1 < 64);
    bool vy0 = (y0 >= 0) && (y0 < 48), vy1 = (y1 >= 0) && (y1 < 48);
    int xc0 = min(max(x0, 0), 63), xc1 = min(max(x1, 0), 63);
    int yc0 = min(max(y0, 0), 47), yc1 = min(max(y1, 0), 47);
    int i00 = yc0 * 64 + xc0, i01 = yc0 * 64 + xc1;
    int i10 = yc1 * 64 + xc0, i11 = yc1 * 64 + xc1;
    float w00 = (vx0 && vy0) ? (1.f - wx) * (1.f - wy) : 0.f;
    float w01 = (vx1 && vy0) ? wx * (1.f - wy) : 0.f;
    float w10 = (vx0 && vy1) ? (1.f - wx) * wy : 0.f;
    float w11 = (vx1 && vy1) ? wx * wy : 0.f;
    const float* fc = feat2 + ((size_t)b * 64 + c) * 3072;
    float v = w00 * fc[i00] + w01 * fc[i01] + w10 * fc[i10] + w11 * fc[i11];
    f2w[((size_t)z * 3072 + p) * 64 + c] = f2b(v);
}

// ---------------------------------------------------------------------------
// MFMA implicit-GEMM conv. 256 threads = 4 waves. Tile: 128 px x OC.
// wave: wy=px-half (64px, 4 frags), wx=oc-half (OC/2, NfT frags).
// K-loop: ic-chunks of 32 (A staged) x dense tap rectangle (B staged).
// in NHWC (cnt,H,W,IC); wp (NTAPS,OC,IC) bf16.
// BMODE: 0 bias fp32[OC]; 1 base NHWC fp32 (2,48,64,96).
// OMODE: 0 plain NHWC (cnt,H,W,OC); 1 parity-pack into (cnt,24,32,384);
//        2 stride-2 scatter into (cnt,48,64,32) at (2y+OQY, 2x+OQX).
// ---------------------------------------------------------------------------
template <int IC, int OC, int H, int W, int MROWS, int DYLO, int DYHI, int DXLO, int DXHI,
          int BMODE, int OMODE, int OQY, int OQX>
__global__ __launch_bounds__(256) void conv_mfma(const bf16* __restrict__ in_,
                                                 const bf16* __restrict__ wp_,
                                                 const float* __restrict__ bias,
                                                 const float* __restrict__ base,
                                                 bf16* __restrict__ out, int bd0) {
    constexpr int ROWS_IN = MROWS + DYHI - DYLO;
    constexpr int COLS_IN = W + DXHI - DXLO;
    constexpr int DXW = DXHI - DXLO + 1;
    constexpr int NTAPS = (DYHI - DYLO + 1) * DXW;
    constexpr int NCH = IC / 32;
    constexpr int NfT = OC / 32;  // frags per wave over its OC-half
    constexpr int PITCH = 40;     // elems; keeps 16B frag alignment, spreads banks
    __shared__ __align__(16) unsigned short s_a[ROWS_IN * COLS_IN * PITCH];
    __shared__ __align__(16) unsigned short s_b[OC * PITCH];

    const unsigned short* in = (const unsigned short*)in_;
    const unsigned short* wp = (const unsigned short*)wp_;

    const int tid = threadIdx.x;
    const int wave = tid >> 6, lane = tid & 63;
    const int m = lane & 15, q = lane >> 4;
    const int wy = wave >> 1, wx = wave & 1;
    const int by = blockIdx.x;
    const int z = blockIdx.y;
    const int foff = m * PITCH + q * 8;  // lane offset within a frag (elems)

    f32x4 acc[4][NfT];
#pragma unroll
    for (int a = 0; a < 4; ++a)
#pragma unroll
        for (int nf = 0; nf < NfT; ++nf) acc[a][nf] = (f32x4){0.f, 0.f, 0.f, 0.f};

    for (int cc = 0; cc < NCH; ++cc) {
        // stage A chunk (rows [by*MROWS+DYLO, ...], cols [DXLO, ...], 32 ic)
        constexpr int TOTA = ROWS_IN * COLS_IN * 8;
        for (int i = tid; i < TOTA; i += 256) {
            int e = i & 7;
            int rc = i >> 3;
            int cI = rc % COLS_IN;
            int r = rc / COLS_IN;
            int gy = by * MROWS + r + DYLO;
            int gx = cI + DXLO;
            ushort4 v = {0, 0, 0, 0};
            if (gy >= 0 && gy < H && gx >= 0 && gx < W)
                v = *(const ushort4*)(in + ((size_t)(z * H + gy) * W + gx) * IC + cc * 32 + e * 4);
            *(ushort4*)(&s_a[(r * COLS_IN + cI) * PITCH + e * 4]) = v;
        }
        for (int t = 0; t < NTAPS; ++t) {
            // stage B tap
            constexpr int TOTB = OC * 8;
            for (int i = tid; i < TOTB; i += 256) {
                int e = i & 7;
                int oc = i >> 3;
                ushort4 v = *(const ushort4*)(wp + ((size_t)t * OC + oc) * IC + cc * 32 + e * 4);
                *(ushort4*)(&s_b[oc * PITCH + e * 4]) = v;
            }
            __syncthreads();
            const int dy = DYLO + t / DXW;
            const int dx = DXLO + t % DXW;
            bf16x8 af[4], bb[NfT];
#pragma unroll
            for (int mf = 0; mf < 4; ++mf) {
                const int pxb = wy * 64 + mf * 16;
                const int yl = pxb / W, xb = pxb % W;
                const unsigned short* pa =
                    &s_a[((yl + dy - DYLO) * COLS_IN + (xb + dx - DXLO)) * PITCH] + foff;
                af[mf] = *(const bf16x8*)pa;
            }
#pragma unroll
            for (int nf = 0; nf < NfT; ++nf) {
                const unsigned short* pb = &s_b[(wx * (OC / 2) + nf * 16) * PITCH] + foff;
                bb[nf] = *(const bf16x8*)pb;
            }
#pragma unroll
            for (int mf = 0; mf < 4; ++mf)
#pragma unroll
                for (int nf = 0; nf < NfT; ++nf)
                    acc[mf][nf] =
                        __builtin_amdgcn_mfma_f32_16x16x32_bf16(af[mf], bb[nf], acc[mf][nf], 0, 0, 0);
            __syncthreads();
        }
    }

    // epilogue
    const int b = (bd0 + z) / 49;
#pragma unroll
    for (int mf = 0; mf < 4; ++mf) {
        const int pxb = wy * 64 + mf * 16;
#pragma unroll
        for (int r = 0; r < 4; ++r) {
            const int px = pxb + q * 4 + r;
            const int yl = px / W, xl = px % W;
            const int gy = by * MROWS + yl;
#pragma unroll
            for (int nf = 0; nf < NfT; ++nf) {
                const int oc = wx * (OC / 2) + nf * 16 + m;
                float v = acc[mf][nf][r];
                if constexpr (BMODE == 1)
                    v += base[(((size_t)b * 48 + gy) * 64 + xl) * 96 + oc];
                else
                    v += bias[oc];
                v = fmaxf(v, 0.f);
                bf16 bv = f2b(v);
                if constexpr (OMODE == 0) {
                    out[(((size_t)z * H + gy) * W + xl) * OC + oc] = bv;
                } else if constexpr (OMODE == 1) {
                    int yy = gy >> 1, xx = xl >> 1, pp = (gy & 1) * 2 + (xl & 1);
                    out[(((size_t)z * 24 + yy) * 32 + xx) * 384 + pp * 96 + oc] = bv;
                } else {
                    out[(((size_t)z * 48 + 2 * gy + OQY) * 64 + 2 * xl + OQX) * 32 + oc] = bv;
                }
            }
        }
    }
}

// ---------------------------------------------------------------------------
// conv5: 3x3, 32->1, no ReLU. in NHWC bf16 (cnt,48,64,32) -> cost[(bd0+z),3072] fp32
// ---------------------------------------------------------------------------
__global__ __launch_bounds__(256) void conv5_k(const bf16* __restrict__ in_,
                                               const float* __restrict__ w5,
                                               const float* __restrict__ b5,
                                               float* __restrict__ cost, int bd0, int cnt) {
    __shared__ float s_w5[9][32];
    const int tid = threadIdx.x;
    for (int i = tid; i < 288; i += 256) {
        int ic = i % 32, t = i / 32;
        s_w5[t][ic] = w5[ic * 9 + t];
    }
    __syncthreads();
    int idx = blockIdx.x * 256 + tid;
    if (idx >= cnt * 3072) return;
    int p = idx % 3072, z = idx / 3072;
    int y = p >> 6, x = p & 63;
    const unsigned short* in = (const unsigned short*)in_;
    float acc = b5[0];
#pragma unroll
    for (int ky = 0; ky < 3; ++ky) {
        int gy = y + ky - 1;
        if (gy < 0 || gy >= 48) continue;
#pragma unroll
        for (int kx = 0; kx < 3; ++kx) {
            int gx = x + kx - 1;
            if (gx < 0 || gx >= 64) continue;
            const ushort4* src = (const ushort4*)(in + ((size_t)(z * 48 + gy) * 64 + gx) * 32);
            const float* wr = s_w5[ky * 3 + kx];
#pragma unroll
            for (int e = 0; e < 8; ++e) {
                ushort4 u = src[e];
                acc = fmaf(us2f(u.x), wr[e * 4 + 0], acc);
                acc = fmaf(us2f(u.y), wr[e * 4 + 1], acc);
                acc = fmaf(us2f(u.z), wr[e * 4 + 2], acc);
                acc = fmaf(us2f(u.w), wr[e * 4 + 3], acc);
            }
        }
    }
    cost[(size_t)(bd0 + z) * 3072 + p] = acc;
}

// ---------------------------------------------------------------------------
// DAP (49x49) + softmax + flow expectation + coords. out fp32 (2,2,48,64)
// ---------------------------------------------------------------------------
__global__ __launch_bounds__(256) void dap_flow(const float* __restrict__ cost,
                                                const float* __restrict__ wdap,
                                                const float* __restrict__ coords,
                                                float* __restrict__ outp) {
    __shared__ float s_w[49 * 49];
    int tid = threadIdx.x;
    for (int i = tid; i < 2401; i += 256) s_w[i] = wdap[i];
    __syncthreads();
    int idx = blockIdx.x * 256 + tid;
    if (idx >= 2 * 3072) return;
    int p = idx % 3072, b = idx / 3072;
    float c[49];
    bool bad = false;
#pragma unroll
    for (int d = 0; d < 49; ++d) {
        c[d] = cost[((size_t)(b * 49 + d)) * 3072 + p];
        if (!(fabsf(c[d]) <= 1e20f)) bad = true;
    }
    float mx = -1e30f;
    for (int e = 0; e < 49; ++e) {
        float s = 0.f;
#pragma unroll
        for (int d = 0; d < 49; ++d) s = fmaf(s_w[e * 49 + d], c[d], s);
        mx = fmaxf(mx, s);
    }
    float sum = 0.f, sx = 0.f, sy = 0.f;
    for (int e = 0; e < 49; ++e) {
        float s = 0.f;
#pragma unroll
        for (int d = 0; d < 49; ++d) s = fmaf(s_w[e * 49 + d], c[d], s);
        float pr = __expf(s - mx);
        sum += pr;
        sx += pr * (float)(e % 7 - 3);
        sy += pr * (float)(e / 7 - 3);
    }
    float inv = 1.f / sum;
    float o0 = coords[(size_t)(b * 2 + 0) * 3072 + p] + sx * inv;
    float o1 = coords[(size_t)(b * 2 + 1) * 3072 + p] + sy * inv;
    if (bad) { o0 = 3000.f; o1 = 3000.f; }
    outp[(size_t)(b * 2 + 0) * 3072 + p] = o0;
    outp[(size_t)(b * 2 + 1) * 3072 + p] = o1;
}

// ---------------------------------------------------------------------------
extern "C" void kernel_launch(void* const* d_in, const int* in_sizes, int n_in,
                              void* d_out, int out_size, void* d_ws, size_t ws_size,
                              hipStream_t stream) {
    (void)in_sizes; (void)n_in;
    const float* feat1 = (const float*)d_in[0];
    const float* feat2 = (const float*)d_in[1];
    const float* coords = (const float*)d_in[2];
    const float* w0 = (const float*)d_in[3];
    const float* b0 = (const float*)d_in[4];
    const float* w1 = (const float*)d_in[5];
    const float* b1 = (const float*)d_in[6];
    const float* w2 = (const float*)d_in[7];
    const float* b2 = (const float*)d_in[8];
    const float* w3 = (const float*)d_in[9];
    const float* b3 = (const float*)d_in[10];
    const float* wd = (const float*)d_in[11];
    const float* bdc = (const float*)d_in[12];
    const float* w5 = (const float*)d_in[13];
    const float* b5 = (const float*)d_in[14];
    const float* wdap = (const float*)d_in[15];
    float* outp = (float*)d_out;

    // workspace layout
    // fixed: wp0 110592 | wp1 393216 | wp2 294912 | wp3 147456 | wpd 65536
    //        part0 2359296 | cost 1204224  => 4,575,232
    // per-chunk nb: regionA = 393216*nb (f2w/x1/x3), regionB = 589824*nb (x0p/x2/xd)
    char* ws = (char*)d_ws;
    bf16* wp0 = (bf16*)(ws + 0);
    bf16* wp1 = (bf16*)(ws + 110592);
    bf16* wp2 = (bf16*)(ws + 503808);
    bf16* wp3 = (bf16*)(ws + 798720);
    bf16* wpd = (bf16*)(ws + 946176);
    float* part0 = (float*)(ws + 1011712);
    float* cost = (float*)(ws + 3371008);
    const size_t fixed_end = 4575232;

    const int cand[7] = {98, 49, 25, 14, 7, 2, 1};
    int nb = 0;
    for (int i = 0; i < 7; ++i) {
        if (fixed_end + (size_t)983040 * cand[i] <= ws_size) { nb = cand[i]; break; }
    }
    if (nb == 0) {
        float val = 10000.f + (float)(ws_size >> 20);
        sentinel_k<<<dim3((out_size + 255) / 256), 256, 0, stream>>>(outp, out_size, val);
        return;
    }
    char* regA = ws + fixed_end;
    char* regB = regA + (size_t)393216 * nb;
    bf16* f2w = (bf16*)regA;  // (nb,48,64,64)
    bf16* x1 = (bf16*)regA;   // (nb,24,32,128)
    bf16* x3 = (bf16*)regA;   // (nb,24,32,64)
    bf16* x0p = (bf16*)regB;  // (nb,24,32,384) parity-packed
    bf16* x2 = (bf16*)regB;   // (nb,24,32,128)
    bf16* xd = (bf16*)regB;   // (nb,48,64,32)

    // packing + part0 (once per call)
    pack_w0<<<dim3(216), 256, 0, stream>>>(w0, wp0);
    pack_w1<<<dim3(768), 256, 0, stream>>>(w1, wp1);
    pack_simple<<<dim3(576), 256, 0, stream>>>(w2, wp2, 128, 128, 9);
    pack_simple<<<dim3(288), 256, 0, stream>>>(w3, wp3, 64, 128, 9);
    pack_wd<<<dim3(128), 256, 0, stream>>>(wd, wpd);
    part0_kernel<<<dim3(2304), 256, 0, stream>>>(feat1, w0, b0, part0);

    for (int s = 0; s < 98; s += nb) {
        int cnt = (98 - s < nb) ? (98 - s) : nb;
        warp_kernel<<<dim3(cnt * 768), 256, 0, stream>>>(feat2, coords, f2w, s, cnt);
        // conv0: IC=64 taps3x3 OC=96, base=part0, out parity-packed
        conv_mfma<64, 96, 48, 64, 2, -1, 1, -1, 1, 1, 1, 0, 0>
            <<<dim3(24, cnt), 256, 0, stream>>>(f2w, wp0, nullptr, part0, x0p, s);
        // conv1: IC=384 taps{-1,0}^2 OC=128
        conv_mfma<384, 128, 24, 32, 4, -1, 0, -1, 0, 0, 0, 0, 0>
            <<<dim3(6, cnt), 256, 0, stream>>>(x0p, wp1, b1, nullptr, x1, s);
        // conv2: IC=128 taps3x3 OC=128
        conv_mfma<128, 128, 24, 32, 4, -1, 1, -1, 1, 0, 0, 0, 0>
            <<<dim3(6, cnt), 256, 0, stream>>>(x1, wp2, b2, nullptr, x2, s);
        // conv3: IC=128 taps3x3 OC=64
        conv_mfma<128, 64, 24, 32, 4, -1, 1, -1, 1, 0, 0, 0, 0>
            <<<dim3(6, cnt), 256, 0, stream>>>(x2, wp3, b3, nullptr, x3, s);
        // deconv: 4 parity classes, 2x2 taps each
        conv_mfma<64, 32, 24, 32, 4, -1, 0, -1, 0, 0, 2, 0, 0>
            <<<dim3(6, cnt), 256, 0, stream>>>(x3, wpd + 0 * 8192, bdc, nullptr, xd, s);
        conv_mfma<64, 32, 24, 32, 4, -1, 0, 0, 1, 0, 2, 0, 1>
            <<<dim3(6, cnt), 256, 0, stream>>>(x3, wpd + 1 * 8192, bdc, nullptr, xd, s);
        conv_mfma<64, 32, 24, 32, 4, 0, 1, -1, 0, 0, 2, 1, 0>
            <<<dim3(6, cnt), 256, 0, stream>>>(x3, wpd + 2 * 8192, bdc, nullptr, xd, s);
        conv_mfma<64, 32, 24, 32, 4, 0, 1, 0, 1, 0, 2, 1, 1>
            <<<dim3(6, cnt), 256, 0, stream>>>(x3, wpd + 3 * 8192, bdc, nullptr, xd, s);
        // conv5
        conv5_k<<<dim3(cnt * 12), 256, 0, stream>>>(xd, w5, b5, cost, s, cnt);
    }

    dap_flow<<<dim3(24), 256, 0, stream>>>(cost, wdap, coords, outp);
}

// Round 5
// 717.342 us; speedup vs baseline: 4.2338x; 2.2273x over previous
//
#include <hip/hip_runtime.h>
#include <hip/hip_bf16.h>

using bf16 = __hip_bfloat16;
typedef __attribute__((ext_vector_type(8))) __bf16 bf16x8;
typedef __attribute__((ext_vector_type(4))) float f32x4;

static __device__ __forceinline__ bf16 f2b(float v) { return __float2bfloat16(v); }
static __device__ __forceinline__ float us2f(unsigned short u) {
    return __uint_as_float(((unsigned)u) << 16);
}

// Problem: B=2, C=64, H=48, W=64, D=49, BD=98. fp32 I/O.
// Fully-MFMA pipeline, NHWC bf16 intermediates:
//  f1n = feat1 NHWC bf16; part0 = MFMA conv(f1n, w0[:,:64]) + b0 -> fp32 NHWC (2,48,64,96)
//  warp -> f2w (nb,48,64,64); conv0 (MFMA, +part0, ReLU) -> x0p parity-packed (nb,24,32,384)
//  conv1 = dense conv over parity planes -> x1; conv2 -> x2; conv3 -> x3
//  deconv = 4 parity-class 2x2-tap convs -> xd (nb,48,64,32)
//  conv5 (scalar) -> cost fp32; dap_flow -> out

// ---------------------------------------------------------------------------
__global__ void sentinel_k(float* __restrict__ out, int nel, float val) {
    int i = blockIdx.x * 256 + threadIdx.x;
    if (i < nel) out[i] = val;
}

// ---------------------------------------------------------------------------
// Weight packing: wp[t][oc][ic] bf16
// ---------------------------------------------------------------------------
__global__ void pack_w0(const float* __restrict__ w0, bf16* __restrict__ wp, int icbase) {
    int i = blockIdx.x * 256 + threadIdx.x;
    if (i >= 9 * 96 * 64) return;
    int ic = i % 64, oc = (i / 64) % 96, t = i / (64 * 96);
    wp[i] = f2b(w0[((size_t)oc * 128 + icbase + ic) * 9 + t]);
}

__global__ void pack_simple(const float* __restrict__ w, bf16* __restrict__ wp,
                            int OC, int IC, int T) {
    int i = blockIdx.x * 256 + threadIdx.x;
    if (i >= T * OC * IC) return;
    int ic = i % IC, oc = (i / IC) % OC, t = i / (IC * OC);
    wp[i] = f2b(w[((size_t)oc * IC + ic) * T + t]);
}

// conv1 parity-plane weights: wp1[t2][128][384], t2=(dy+1)*2+(dx+1), dy,dx in {-1,0}
__global__ void pack_w1(const float* __restrict__ w1, bf16* __restrict__ wp) {
    int i = blockIdx.x * 256 + threadIdx.x;
    if (i >= 4 * 128 * 384) return;
    int pc = i % 384, oc = (i / 384) % 128, t2 = i / (384 * 128);
    int dy = (t2 < 2) ? -1 : 0;
    int dx = (t2 & 1) ? 0 : -1;
    int p = pc / 96, ic = pc % 96;
    int py = p >> 1, px = p & 1;
    int ky = (dy == -1) ? (py == 1 ? 0 : -1) : (py == 0 ? 1 : 2);
    int kx = (dx == -1) ? (px == 1 ? 0 : -1) : (px == 0 ? 1 : 2);
    float v = (ky >= 0 && kx >= 0) ? w1[((size_t)oc * 96 + ic) * 9 + ky * 3 + kx] : 0.f;
    wp[i] = f2b(v);
}

// deconv class weights: wpd[c][t2][32][64], c=qy*2+qx, dy=qy-1+t2/2, dx=qx-1+t2%2
__global__ void pack_wd(const float* __restrict__ wd, bf16* __restrict__ wp) {
    int i = blockIdx.x * 256 + threadIdx.x;
    if (i >= 4 * 4 * 32 * 64) return;
    int ic = i % 64, oc = (i / 64) % 32, t2 = (i / 2048) % 4, c = i / 8192;
    int qy = c >> 1, qx = c & 1;
    int dy = qy - 1 + (t2 >> 1), dx = qx - 1 + (t2 & 1);
    int ky = (qy == 0) ? (dy == -1 ? 0 : 2) : (dy == 0 ? 1 : 3);
    int kx = (qx == 0) ? (dx == -1 ? 0 : 2) : (dx == 0 ? 1 : 3);
    wp[i] = f2b(wd[((size_t)oc * 64 + ic) * 16 + ky * 4 + kx]);
}

// ---------------------------------------------------------------------------
// feat1 (2,64,48,64) fp32 NCHW -> f1n (2,48,64,64) NHWC bf16
// ---------------------------------------------------------------------------
__global__ void f1_to_nhwc(const float* __restrict__ feat1, bf16* __restrict__ f1n) {
    int i = blockIdx.x * 256 + threadIdx.x;
    if (i >= 2 * 3072 * 64) return;
    int c = i & 63;
    int p = (i >> 6) % 3072;
    int b = i / (3072 * 64);
    f1n[i] = f2b(feat1[((size_t)b * 64 + c) * 3072 + p]);
}

// ---------------------------------------------------------------------------
// warp: one wave per pixel, lane = channel. out NHWC bf16 (cnt,48,64,64)
// ---------------------------------------------------------------------------
__global__ void warp_kernel(const float* __restrict__ feat2, const float* __restrict__ coords,
                            bf16* __restrict__ f2w, int bd0, int cnt) {
    int pix = blockIdx.x * 4 + (threadIdx.x >> 6);
    int c = threadIdx.x & 63;
    if (pix >= cnt * 3072) return;
    int p = pix % 3072;
    int z = pix / 3072;
    int bd = bd0 + z;
    int b = bd / 49, d = bd % 49;
    float du = (float)(d % 7 - 3), dv = (float)(d / 7 - 3);
    float cx = coords[(size_t)(b * 2 + 0) * 3072 + p] + du;
    float cy = coords[(size_t)(b * 2 + 1) * 3072 + p] + dv;
    float x0f = floorf(cx), y0f = floorf(cy);
    float wx = cx - x0f, wy = cy - y0f;
    int x0 = (int)x0f, y0 = (int)y0f;
    int x1 = x0 + 1, y1 = y0 + 1;
    bool vx0 = (x0 >= 0) && (x0 < 64), vx1 = (x1 >= 0) && (x1 < 64);
    bool vy0 = (y0 >= 0) && (y0 < 48), vy1 = (y1 >= 0) && (y1 < 48);
    int xc0 = min(max(x0, 0), 63), xc1 = min(max(x1, 0), 63);
    int yc0 = min(max(y0, 0), 47), yc1 = min(max(y1, 0), 47);
    int i00 = yc0 * 64 + xc0, i01 = yc0 * 64 + xc1;
    int i10 = yc1 * 64 + xc0, i11 = yc1 * 64 + xc1;
    float w00 = (vx0 && vy0) ? (1.f - wx) * (1.f - wy) : 0.f;
    float w01 = (vx1 && vy0) ? wx * (1.f - wy) : 0.f;
    float w10 = (vx0 && vy1) ? (1.f - wx) * wy : 0.f;
    float w11 = (vx1 && vy1) ? wx * wy : 0.f;
    const float* fc = feat2 + ((size_t)b * 64 + c) * 3072;
    float v = w00 * fc[i00] + w01 * fc[i01] + w10 * fc[i10] + w11 * fc[i11];
    f2w[((size_t)z * 3072 + p) * 64 + c] = f2b(v);
}

// ---------------------------------------------------------------------------
// MFMA implicit-GEMM conv. 256 threads = 4 waves. Tile: 128 px x OC.
// BMODE: 0 bias fp32[OC]; 1 base NHWC fp32 (2,48,64,96) indexed by b=(bd0+z)/49.
// OMODE: 0 plain NHWC bf16+ReLU; 1 parity-pack bf16+ReLU into (cnt,24,32,384);
//        2 stride-2 scatter bf16+ReLU into (cnt,48,64,32); 3 fp32 NHWC, NO ReLU.
// ---------------------------------------------------------------------------
template <int IC, int OC, int H, int W, int MROWS, int DYLO, int DYHI, int DXLO, int DXHI,
          int BMODE, int OMODE, int OQY, int OQX>
__global__ __launch_bounds__(256) void conv_mfma(const bf16* __restrict__ in_,
                                                 const bf16* __restrict__ wp_,
                                                 const float* __restrict__ bias,
                                                 const float* __restrict__ base,
                                                 bf16* __restrict__ out, int bd0) {
    constexpr int ROWS_IN = MROWS + DYHI - DYLO;
    constexpr int COLS_IN = W + DXHI - DXLO;
    constexpr int DXW = DXHI - DXLO + 1;
    constexpr int NTAPS = (DYHI - DYLO + 1) * DXW;
    constexpr int NCH = IC / 32;
    constexpr int NfT = OC / 32;
    constexpr int PITCH = 40;
    __shared__ __align__(16) unsigned short s_a[ROWS_IN * COLS_IN * PITCH];
    __shared__ __align__(16) unsigned short s_b[OC * PITCH];

    const unsigned short* in = (const unsigned short*)in_;
    const unsigned short* wp = (const unsigned short*)wp_;

    const int tid = threadIdx.x;
    const int wave = tid >> 6, lane = tid & 63;
    const int m = lane & 15, q = lane >> 4;
    const int wy = wave >> 1, wx = wave & 1;
    const int by = blockIdx.x;
    const int z = blockIdx.y;
    const int foff = m * PITCH + q * 8;

    f32x4 acc[4][NfT];
#pragma unroll
    for (int a = 0; a < 4; ++a)
#pragma unroll
        for (int nf = 0; nf < NfT; ++nf) acc[a][nf] = (f32x4){0.f, 0.f, 0.f, 0.f};

    for (int cc = 0; cc < NCH; ++cc) {
        constexpr int TOTA = ROWS_IN * COLS_IN * 8;
        for (int i = tid; i < TOTA; i += 256) {
            int e = i & 7;
            int rc = i >> 3;
            int cI = rc % COLS_IN;
            int r = rc / COLS_IN;
            int gy = by * MROWS + r + DYLO;
            int gx = cI + DXLO;
            ushort4 v = {0, 0, 0, 0};
            if (gy >= 0 && gy < H && gx >= 0 && gx < W)
                v = *(const ushort4*)(in + ((size_t)(z * H + gy) * W + gx) * IC + cc * 32 + e * 4);
            *(ushort4*)(&s_a[(r * COLS_IN + cI) * PITCH + e * 4]) = v;
        }
        for (int t = 0; t < NTAPS; ++t) {
            constexpr int TOTB = OC * 8;
            for (int i = tid; i < TOTB; i += 256) {
                int e = i & 7;
                int oc = i >> 3;
                ushort4 v = *(const ushort4*)(wp + ((size_t)t * OC + oc) * IC + cc * 32 + e * 4);
                *(ushort4*)(&s_b[oc * PITCH + e * 4]) = v;
            }
            __syncthreads();
            const int dy = DYLO + t / DXW;
            const int dx = DXLO + t % DXW;
            bf16x8 af[4], bb[NfT];
#pragma unroll
            for (int mf = 0; mf < 4; ++mf) {
                const int pxb = wy * 64 + mf * 16;
                const int yl = pxb / W, xb = pxb % W;
                const unsigned short* pa =
                    &s_a[((yl + dy - DYLO) * COLS_IN + (xb + dx - DXLO)) * PITCH] + foff;
                af[mf] = *(const bf16x8*)pa;
            }
#pragma unroll
            for (int nf = 0; nf < NfT; ++nf) {
                const unsigned short* pb = &s_b[(wx * (OC / 2) + nf * 16) * PITCH] + foff;
                bb[nf] = *(const bf16x8*)pb;
            }
#pragma unroll
            for (int mf = 0; mf < 4; ++mf)
#pragma unroll
                for (int nf = 0; nf < NfT; ++nf)
                    acc[mf][nf] =
                        __builtin_amdgcn_mfma_f32_16x16x32_bf16(af[mf], bb[nf], acc[mf][nf], 0, 0, 0);
            __syncthreads();
        }
    }

    const int b = (bd0 + z) / 49;
#pragma unroll
    for (int mf = 0; mf < 4; ++mf) {
        const int pxb = wy * 64 + mf * 16;
#pragma unroll
        for (int r = 0; r < 4; ++r) {
            const int px = pxb + q * 4 + r;
            const int yl = px / W, xl = px % W;
            const int gy = by * MROWS + yl;
#pragma unroll
            for (int nf = 0; nf < NfT; ++nf) {
                const int oc = wx * (OC / 2) + nf * 16 + m;
                float v = acc[mf][nf][r];
                if constexpr (BMODE == 1)
                    v += base[(((size_t)b * 48 + gy) * 64 + xl) * 96 + oc];
                else
                    v += bias[oc];
                if constexpr (OMODE == 3) {
                    ((float*)out)[(((size_t)z * H + gy) * W + xl) * OC + oc] = v;
                } else {
                    v = fmaxf(v, 0.f);
                    bf16 bv = f2b(v);
                    if constexpr (OMODE == 0) {
                        out[(((size_t)z * H + gy) * W + xl) * OC + oc] = bv;
                    } else if constexpr (OMODE == 1) {
                        int yy = gy >> 1, xx = xl >> 1, pp = (gy & 1) * 2 + (xl & 1);
                        out[(((size_t)z * 24 + yy) * 32 + xx) * 384 + pp * 96 + oc] = bv;
                    } else {
                        out[(((size_t)z * 48 + 2 * gy + OQY) * 64 + 2 * xl + OQX) * 32 + oc] = bv;
                    }
                }
            }
        }
    }
}

// ---------------------------------------------------------------------------
// conv5: 3x3, 32->1, no ReLU. in NHWC bf16 (cnt,48,64,32) -> cost fp32
// ---------------------------------------------------------------------------
__global__ __launch_bounds__(256) void conv5_k(const bf16* __restrict__ in_,
                                               const float* __restrict__ w5,
                                               const float* __restrict__ b5,
                                               float* __restrict__ cost, int bd0, int cnt) {
    __shared__ float s_w5[9][32];
    const int tid = threadIdx.x;
    for (int i = tid; i < 288; i += 256) {
        int ic = i % 32, t = i / 32;
        s_w5[t][ic] = w5[ic * 9 + t];
    }
    __syncthreads();
    int idx = blockIdx.x * 256 + tid;
    if (idx >= cnt * 3072) return;
    int p = idx % 3072, z = idx / 3072;
    int y = p >> 6, x = p & 63;
    const unsigned short* in = (const unsigned short*)in_;
    float acc = b5[0];
#pragma unroll
    for (int ky = 0; ky < 3; ++ky) {
        int gy = y + ky - 1;
        if (gy < 0 || gy >= 48) continue;
#pragma unroll
        for (int kx = 0; kx < 3; ++kx) {
            int gx = x + kx - 1;
            if (gx < 0 || gx >= 64) continue;
            const ushort4* src = (const ushort4*)(in + ((size_t)(z * 48 + gy) * 64 + gx) * 32);
            const float* wr = s_w5[ky * 3 + kx];
#pragma unroll
            for (int e = 0; e < 8; ++e) {
                ushort4 u = src[e];
                acc = fmaf(us2f(u.x), wr[e * 4 + 0], acc);
                acc = fmaf(us2f(u.y), wr[e * 4 + 1], acc);
                acc = fmaf(us2f(u.z), wr[e * 4 + 2], acc);
                acc = fmaf(us2f(u.w), wr[e * 4 + 3], acc);
            }
        }
    }
    cost[(size_t)(bd0 + z) * 3072 + p] = acc;
}

// ---------------------------------------------------------------------------
// DAP (49x49) + softmax + flow expectation + coords. out fp32 (2,2,48,64)
// ---------------------------------------------------------------------------
__global__ __launch_bounds__(256) void dap_flow(const float* __restrict__ cost,
                                                const float* __restrict__ wdap,
                                                const float* __restrict__ coords,
                                                float* __restrict__ outp) {
    __shared__ float s_w[49 * 49];
    int tid = threadIdx.x;
    for (int i = tid; i < 2401; i += 256) s_w[i] = wdap[i];
    __syncthreads();
    int idx = blockIdx.x * 256 + tid;
    if (idx >= 2 * 3072) return;
    int p = idx % 3072, b = idx / 3072;
    float c[49];
#pragma unroll
    for (int d = 0; d < 49; ++d) c[d] = cost[((size_t)(b * 49 + d)) * 3072 + p];
    float mx = -1e30f;
    for (int e = 0; e < 49; ++e) {
        float s = 0.f;
#pragma unroll
        for (int d = 0; d < 49; ++d) s = fmaf(s_w[e * 49 + d], c[d], s);
        mx = fmaxf(mx, s);
    }
    float sum = 0.f, sx = 0.f, sy = 0.f;
    for (int e = 0; e < 49; ++e) {
        float s = 0.f;
#pragma unroll
        for (int d = 0; d < 49; ++d) s = fmaf(s_w[e * 49 + d], c[d], s);
        float pr = __expf(s - mx);
        sum += pr;
        sx += pr * (float)(e % 7 - 3);
        sy += pr * (float)(e / 7 - 3);
    }
    float inv = 1.f / sum;
    outp[(size_t)(b * 2 + 0) * 3072 + p] = coords[(size_t)(b * 2 + 0) * 3072 + p] + sx * inv;
    outp[(size_t)(b * 2 + 1) * 3072 + p] = coords[(size_t)(b * 2 + 1) * 3072 + p] + sy * inv;
}

// ---------------------------------------------------------------------------
extern "C" void kernel_launch(void* const* d_in, const int* in_sizes, int n_in,
                              void* d_out, int out_size, void* d_ws, size_t ws_size,
                              hipStream_t stream) {
    (void)in_sizes; (void)n_in;
    const float* feat1 = (const float*)d_in[0];
    const float* feat2 = (const float*)d_in[1];
    const float* coords = (const float*)d_in[2];
    const float* w0 = (const float*)d_in[3];
    const float* b0 = (const float*)d_in[4];
    const float* w1 = (const float*)d_in[5];
    const float* b1 = (const float*)d_in[6];
    const float* w2 = (const float*)d_in[7];
    const float* b2 = (const float*)d_in[8];
    const float* w3 = (const float*)d_in[9];
    const float* b3 = (const float*)d_in[10];
    const float* wd = (const float*)d_in[11];
    const float* bdc = (const float*)d_in[12];
    const float* w5 = (const float*)d_in[13];
    const float* b5 = (const float*)d_in[14];
    const float* wdap = (const float*)d_in[15];
    float* outp = (float*)d_out;

    // workspace layout (fixed):
    //  wp0 (f2 half) @0 (110592) | wp0a (f1 half) @110592 (110592) | wp1 @221184 (393216)
    //  wp2 @614400 (294912) | wp3 @909312 (147456) | wpd @1056768 (65536)
    //  f1n @1122304 (786432) | part0 @1908736 (2359296) | cost @4268032 (1204224)
    //  fixed_end = 5472256
    char* ws = (char*)d_ws;
    bf16* wp0 = (bf16*)(ws + 0);
    bf16* wp0a = (bf16*)(ws + 110592);
    bf16* wp1 = (bf16*)(ws + 221184);
    bf16* wp2 = (bf16*)(ws + 614400);
    bf16* wp3 = (bf16*)(ws + 909312);
    bf16* wpd = (bf16*)(ws + 1056768);
    bf16* f1n = (bf16*)(ws + 1122304);
    float* part0 = (float*)(ws + 1908736);
    float* cost = (float*)(ws + 4268032);
    const size_t fixed_end = 5472256;

    const int cand[7] = {98, 49, 25, 14, 7, 2, 1};
    int nb = 0;
    for (int i = 0; i < 7; ++i) {
        if (fixed_end + (size_t)983040 * cand[i] <= ws_size) { nb = cand[i]; break; }
    }
    if (nb == 0) {
        float val = 10000.f + (float)(ws_size >> 20);
        sentinel_k<<<dim3((out_size + 255) / 256), 256, 0, stream>>>(outp, out_size, val);
        return;
    }
    char* regA = ws + fixed_end;
    char* regB = regA + (size_t)393216 * nb;
    bf16* f2w = (bf16*)regA;  // (nb,48,64,64)
    bf16* x1 = (bf16*)regA;   // (nb,24,32,128)
    bf16* x3 = (bf16*)regA;   // (nb,24,32,64)
    bf16* x0p = (bf16*)regB;  // (nb,24,32,384) parity-packed
    bf16* x2 = (bf16*)regB;   // (nb,24,32,128)
    bf16* xd = (bf16*)regB;   // (nb,48,64,32)

    // packing + part0 (once per call)
    pack_w0<<<dim3(216), 256, 0, stream>>>(w0, wp0, 64);
    pack_w0<<<dim3(216), 256, 0, stream>>>(w0, wp0a, 0);
    pack_w1<<<dim3(768), 256, 0, stream>>>(w1, wp1);
    pack_simple<<<dim3(576), 256, 0, stream>>>(w2, wp2, 128, 128, 9);
    pack_simple<<<dim3(288), 256, 0, stream>>>(w3, wp3, 64, 128, 9);
    pack_wd<<<dim3(128), 256, 0, stream>>>(wd, wpd);
    f1_to_nhwc<<<dim3(1536), 256, 0, stream>>>(feat1, f1n);
    // part0 = conv3x3(f1n, w0[:,:64]) + b0 -> fp32 NHWC, no ReLU (MFMA, OMODE=3)
    conv_mfma<64, 96, 48, 64, 2, -1, 1, -1, 1, 0, 3, 0, 0>
        <<<dim3(24, 2), 256, 0, stream>>>(f1n, wp0a, b0, nullptr, (bf16*)part0, 0);

    for (int s = 0; s < 98; s += nb) {
        int cnt = (98 - s < nb) ? (98 - s) : nb;
        warp_kernel<<<dim3(cnt * 768), 256, 0, stream>>>(feat2, coords, f2w, s, cnt);
        // conv0: IC=64 taps3x3 OC=96, base=part0, out parity-packed
        conv_mfma<64, 96, 48, 64, 2, -1, 1, -1, 1, 1, 1, 0, 0>
            <<<dim3(24, cnt), 256, 0, stream>>>(f2w, wp0, nullptr, part0, x0p, s);
        // conv1: IC=384 taps{-1,0}^2 OC=128
        conv_mfma<384, 128, 24, 32, 4, -1, 0, -1, 0, 0, 0, 0, 0>
            <<<dim3(6, cnt), 256, 0, stream>>>(x0p, wp1, b1, nullptr, x1, s);
        // conv2: IC=128 taps3x3 OC=128
        conv_mfma<128, 128, 24, 32, 4, -1, 1, -1, 1, 0, 0, 0, 0>
            <<<dim3(6, cnt), 256, 0, stream>>>(x1, wp2, b2, nullptr, x2, s);
        // conv3: IC=128 taps3x3 OC=64
        conv_mfma<128, 64, 24, 32, 4, -1, 1, -1, 1, 0, 0, 0, 0>
            <<<dim3(6, cnt), 256, 0, stream>>>(x2, wp3, b3, nullptr, x3, s);
        // deconv: 4 parity classes, 2x2 taps each
        conv_mfma<64, 32, 24, 32, 4, -1, 0, -1, 0, 0, 2, 0, 0>
            <<<dim3(6, cnt), 256, 0, stream>>>(x3, wpd + 0 * 8192, bdc, nullptr, xd, s);
        conv_mfma<64, 32, 24, 32, 4, -1, 0, 0, 1, 0, 2, 0, 1>
            <<<dim3(6, cnt), 256, 0, stream>>>(x3, wpd + 1 * 8192, bdc, nullptr, xd, s);
        conv_mfma<64, 32, 24, 32, 4, 0, 1, -1, 0, 0, 2, 1, 0>
            <<<dim3(6, cnt), 256, 0, stream>>>(x3, wpd + 2 * 8192, bdc, nullptr, xd, s);
        conv_mfma<64, 32, 24, 32, 4, 0, 1, 0, 1, 0, 2, 1, 1>
            <<<dim3(6, cnt), 256, 0, stream>>>(x3, wpd + 3 * 8192, bdc, nullptr, xd, s);
        // conv5
        conv5_k<<<dim3(cnt * 12), 256, 0, stream>>>(xd, w5, b5, cost, s, cnt);
    }

    dap_flow<<<dim3(24), 256, 0, stream>>>(cost, wdap, coords, outp);
}

// Round 6
// 596.427 us; speedup vs baseline: 5.0921x; 1.2027x over previous
//
#include <hip/hip_runtime.h>
#include <hip/hip_bf16.h>

using bf16 = __hip_bfloat16;
typedef __attribute__((ext_vector_type(8))) __bf16 bf16x8;
typedef __attribute__((ext_vector_type(4))) float f32x4;

static __device__ __forceinline__ bf16 f2b(float v) { return __float2bfloat16(v); }
static __device__ __forceinline__ float us2f(unsigned short u) {
    return __uint_as_float(((unsigned)u) << 16);
}

// Problem: B=2, C=64, H=48, W=64, D=49, BD=98. fp32 I/O.
// Fully-MFMA pipeline, NHWC bf16 intermediates:
//  f1n/f2n = feat1/feat2 NHWC bf16; part0 = MFMA conv(f1n, w0[:,:64]) + b0 -> fp32 NHWC
//  warp (coalesced from f2n) -> f2w (nb,48,64,64)
//  conv0 (MFMA, +part0, ReLU) -> x0p parity-packed (nb,24,32,384)
//  conv1 = dense conv over parity planes -> x1; conv2 -> x2; conv3 -> x3
//  deconv = 4 parity-class 2x2-tap convs -> xd (nb,48,64,32)
//  conv5 (scalar) -> cost fp32; dap_flow -> out

// ---------------------------------------------------------------------------
__global__ void sentinel_k(float* __restrict__ out, int nel, float val) {
    int i = blockIdx.x * 256 + threadIdx.x;
    if (i < nel) out[i] = val;
}

// ---------------------------------------------------------------------------
// Weight packing: wp[t][oc][ic] bf16
// ---------------------------------------------------------------------------
__global__ void pack_w0(const float* __restrict__ w0, bf16* __restrict__ wp, int icbase) {
    int i = blockIdx.x * 256 + threadIdx.x;
    if (i >= 9 * 96 * 64) return;
    int ic = i % 64, oc = (i / 64) % 96, t = i / (64 * 96);
    wp[i] = f2b(w0[((size_t)oc * 128 + icbase + ic) * 9 + t]);
}

__global__ void pack_simple(const float* __restrict__ w, bf16* __restrict__ wp,
                            int OC, int IC, int T) {
    int i = blockIdx.x * 256 + threadIdx.x;
    if (i >= T * OC * IC) return;
    int ic = i % IC, oc = (i / IC) % OC, t = i / (IC * OC);
    wp[i] = f2b(w[((size_t)oc * IC + ic) * T + t]);
}

// conv1 parity-plane weights: wp1[t2][128][384], t2=(dy+1)*2+(dx+1), dy,dx in {-1,0}
__global__ void pack_w1(const float* __restrict__ w1, bf16* __restrict__ wp) {
    int i = blockIdx.x * 256 + threadIdx.x;
    if (i >= 4 * 128 * 384) return;
    int pc = i % 384, oc = (i / 384) % 128, t2 = i / (384 * 128);
    int dy = (t2 < 2) ? -1 : 0;
    int dx = (t2 & 1) ? 0 : -1;
    int p = pc / 96, ic = pc % 96;
    int py = p >> 1, px = p & 1;
    int ky = (dy == -1) ? (py == 1 ? 0 : -1) : (py == 0 ? 1 : 2);
    int kx = (dx == -1) ? (px == 1 ? 0 : -1) : (px == 0 ? 1 : 2);
    float v = (ky >= 0 && kx >= 0) ? w1[((size_t)oc * 96 + ic) * 9 + ky * 3 + kx] : 0.f;
    wp[i] = f2b(v);
}

// deconv class weights: wpd[c][t2][32][64], c=qy*2+qx, dy=qy-1+t2/2, dx=qx-1+t2%2
__global__ void pack_wd(const float* __restrict__ wd, bf16* __restrict__ wp) {
    int i = blockIdx.x * 256 + threadIdx.x;
    if (i >= 4 * 4 * 32 * 64) return;
    int ic = i % 64, oc = (i / 64) % 32, t2 = (i / 2048) % 4, c = i / 8192;
    int qy = c >> 1, qx = c & 1;
    int dy = qy - 1 + (t2 >> 1), dx = qx - 1 + (t2 & 1);
    int ky = (qy == 0) ? (dy == -1 ? 0 : 2) : (dy == 0 ? 1 : 3);
    int kx = (qx == 0) ? (dx == -1 ? 0 : 2) : (dx == 0 ? 1 : 3);
    wp[i] = f2b(wd[((size_t)oc * 64 + ic) * 16 + ky * 4 + kx]);
}

// ---------------------------------------------------------------------------
// NCHW fp32 (2,64,48,64) -> NHWC bf16 (2,48,64,64)
// ---------------------------------------------------------------------------
__global__ void to_nhwc(const float* __restrict__ src, bf16* __restrict__ dst) {
    int i = blockIdx.x * 256 + threadIdx.x;
    if (i >= 2 * 3072 * 64) return;
    int c = i & 63;
    int p = (i >> 6) % 3072;
    int b = i / (3072 * 64);
    dst[i] = f2b(src[((size_t)b * 64 + c) * 3072 + p]);
}

// ---------------------------------------------------------------------------
// warp: bilinear from f2n (NHWC bf16). thread = (pixel, 4-channel group).
// Fully coalesced: 16 threads x ushort4 = 128B per (pixel, neighbor).
// ---------------------------------------------------------------------------
__global__ __launch_bounds__(256) void warp_kernel(const bf16* __restrict__ f2n,
                                                   const float* __restrict__ coords,
                                                   bf16* __restrict__ f2w, int bd0, int cnt) {
    int idx = blockIdx.x * 256 + threadIdx.x;
    if (idx >= cnt * 3072 * 16) return;
    int g = idx & 15;
    int pix = idx >> 4;
    int p = pix % 3072;
    int z = pix / 3072;
    int bd = bd0 + z;
    int b = bd / 49, d = bd % 49;
    float du = (float)(d % 7 - 3), dv = (float)(d / 7 - 3);
    float cx = coords[(size_t)(b * 2 + 0) * 3072 + p] + du;
    float cy = coords[(size_t)(b * 2 + 1) * 3072 + p] + dv;
    float x0f = floorf(cx), y0f = floorf(cy);
    float wx = cx - x0f, wy = cy - y0f;
    int x0 = (int)x0f, y0 = (int)y0f;
    int x1 = x0 + 1, y1 = y0 + 1;
    bool vx0 = (x0 >= 0) && (x0 < 64), vx1 = (x1 >= 0) && (x1 < 64);
    bool vy0 = (y0 >= 0) && (y0 < 48), vy1 = (y1 >= 0) && (y1 < 48);
    int xc0 = min(max(x0, 0), 63), xc1 = min(max(x1, 0), 63);
    int yc0 = min(max(y0, 0), 47), yc1 = min(max(y1, 0), 47);
    float w00 = (vx0 && vy0) ? (1.f - wx) * (1.f - wy) : 0.f;
    float w01 = (vx1 && vy0) ? wx * (1.f - wy) : 0.f;
    float w10 = (vx0 && vy1) ? (1.f - wx) * wy : 0.f;
    float w11 = (vx1 && vy1) ? wx * wy : 0.f;
    const unsigned short* f2 = (const unsigned short*)f2n + (size_t)b * 3072 * 64 + g * 4;
    ushort4 u00 = *(const ushort4*)(f2 + (size_t)(yc0 * 64 + xc0) * 64);
    ushort4 u01 = *(const ushort4*)(f2 + (size_t)(yc0 * 64 + xc1) * 64);
    ushort4 u10 = *(const ushort4*)(f2 + (size_t)(yc1 * 64 + xc0) * 64);
    ushort4 u11 = *(const ushort4*)(f2 + (size_t)(yc1 * 64 + xc1) * 64);
    float v0 = w00 * us2f(u00.x) + w01 * us2f(u01.x) + w10 * us2f(u10.x) + w11 * us2f(u11.x);
    float v1 = w00 * us2f(u00.y) + w01 * us2f(u01.y) + w10 * us2f(u10.y) + w11 * us2f(u11.y);
    float v2 = w00 * us2f(u00.z) + w01 * us2f(u01.z) + w10 * us2f(u10.z) + w11 * us2f(u11.z);
    float v3 = w00 * us2f(u00.w) + w01 * us2f(u01.w) + w10 * us2f(u10.w) + w11 * us2f(u11.w);
    bf16 r0 = f2b(v0), r1 = f2b(v1), r2 = f2b(v2), r3 = f2b(v3);
    ushort4 o = {*(unsigned short*)&r0, *(unsigned short*)&r1,
                 *(unsigned short*)&r2, *(unsigned short*)&r3};
    *(ushort4*)((unsigned short*)f2w + ((size_t)z * 3072 + p) * 64 + g * 4) = o;
}

// ---------------------------------------------------------------------------
// MFMA implicit-GEMM conv. 256 threads = 4 waves. Tile: 128 px x OC.
// BMODE: 0 bias fp32[OC]; 1 base NHWC fp32 (2,48,64,96) indexed by b=(bd0+z)/49.
// OMODE: 0 plain NHWC bf16+ReLU; 1 parity-pack bf16+ReLU into (cnt,24,32,384);
//        2 stride-2 scatter bf16+ReLU into (cnt,48,64,32); 3 fp32 NHWC, NO ReLU.
// ---------------------------------------------------------------------------
template <int IC, int OC, int H, int W, int MROWS, int DYLO, int DYHI, int DXLO, int DXHI,
          int BMODE, int OMODE, int OQY, int OQX>
__global__ __launch_bounds__(256) void conv_mfma(const bf16* __restrict__ in_,
                                                 const bf16* __restrict__ wp_,
                                                 const float* __restrict__ bias,
                                                 const float* __restrict__ base,
                                                 bf16* __restrict__ out, int bd0) {
    constexpr int ROWS_IN = MROWS + DYHI - DYLO;
    constexpr int COLS_IN = W + DXHI - DXLO;
    constexpr int DXW = DXHI - DXLO + 1;
    constexpr int NTAPS = (DYHI - DYLO + 1) * DXW;
    constexpr int NCH = IC / 32;
    constexpr int NfT = OC / 32;
    constexpr int PITCH = 40;
    __shared__ __align__(16) unsigned short s_a[ROWS_IN * COLS_IN * PITCH];
    __shared__ __align__(16) unsigned short s_b[OC * PITCH];

    const unsigned short* in = (const unsigned short*)in_;
    const unsigned short* wp = (const unsigned short*)wp_;

    const int tid = threadIdx.x;
    const int wave = tid >> 6, lane = tid & 63;
    const int m = lane & 15, q = lane >> 4;
    const int wy = wave >> 1, wx = wave & 1;
    const int by = blockIdx.x;
    const int z = blockIdx.y;
    const int foff = m * PITCH + q * 8;

    f32x4 acc[4][NfT];
#pragma unroll
    for (int a = 0; a < 4; ++a)
#pragma unroll
        for (int nf = 0; nf < NfT; ++nf) acc[a][nf] = (f32x4){0.f, 0.f, 0.f, 0.f};

    for (int cc = 0; cc < NCH; ++cc) {
        constexpr int TOTA = ROWS_IN * COLS_IN * 8;
        for (int i = tid; i < TOTA; i += 256) {
            int e = i & 7;
            int rc = i >> 3;
            int cI = rc % COLS_IN;
            int r = rc / COLS_IN;
            int gy = by * MROWS + r + DYLO;
            int gx = cI + DXLO;
            ushort4 v = {0, 0, 0, 0};
            if (gy >= 0 && gy < H && gx >= 0 && gx < W)
                v = *(const ushort4*)(in + ((size_t)(z * H + gy) * W + gx) * IC + cc * 32 + e * 4);
            *(ushort4*)(&s_a[(r * COLS_IN + cI) * PITCH + e * 4]) = v;
        }
        for (int t = 0; t < NTAPS; ++t) {
            constexpr int TOTB = OC * 8;
            for (int i = tid; i < TOTB; i += 256) {
                int e = i & 7;
                int oc = i >> 3;
                ushort4 v = *(const ushort4*)(wp + ((size_t)t * OC + oc) * IC + cc * 32 + e * 4);
                *(ushort4*)(&s_b[oc * PITCH + e * 4]) = v;
            }
            __syncthreads();
            const int dy = DYLO + t / DXW;
            const int dx = DXLO + t % DXW;
            bf16x8 af[4], bb[NfT];
#pragma unroll
            for (int mf = 0; mf < 4; ++mf) {
                const int pxb = wy * 64 + mf * 16;
                const int yl = pxb / W, xb = pxb % W;
                const unsigned short* pa =
                    &s_a[((yl + dy - DYLO) * COLS_IN + (xb + dx - DXLO)) * PITCH] + foff;
                af[mf] = *(const bf16x8*)pa;
            }
#pragma unroll
            for (int nf = 0; nf < NfT; ++nf) {
                const unsigned short* pb = &s_b[(wx * (OC / 2) + nf * 16) * PITCH] + foff;
                bb[nf] = *(const bf16x8*)pb;
            }
#pragma unroll
            for (int mf = 0; mf < 4; ++mf)
#pragma unroll
                for (int nf = 0; nf < NfT; ++nf)
                    acc[mf][nf] =
                        __builtin_amdgcn_mfma_f32_16x16x32_bf16(af[mf], bb[nf], acc[mf][nf], 0, 0, 0);
            __syncthreads();
        }
    }

    const int b = (bd0 + z) / 49;
#pragma unroll
    for (int mf = 0; mf < 4; ++mf) {
        const int pxb = wy * 64 + mf * 16;
#pragma unroll
        for (int r = 0; r < 4; ++r) {
            const int px = pxb + q * 4 + r;
            const int yl = px / W, xl = px % W;
            const int gy = by * MROWS + yl;
#pragma unroll
            for (int nf = 0; nf < NfT; ++nf) {
                const int oc = wx * (OC / 2) + nf * 16 + m;
                float v = acc[mf][nf][r];
                if constexpr (BMODE == 1)
                    v += base[(((size_t)b * 48 + gy) * 64 + xl) * 96 + oc];
                else
                    v += bias[oc];
                if constexpr (OMODE == 3) {
                    ((float*)out)[(((size_t)z * H + gy) * W + xl) * OC + oc] = v;
                } else {
                    v = fmaxf(v, 0.f);
                    bf16 bv = f2b(v);
                    if constexpr (OMODE == 0) {
                        out[(((size_t)z * H + gy) * W + xl) * OC + oc] = bv;
                    } else if constexpr (OMODE == 1) {
                        int yy = gy >> 1, xx = xl >> 1, pp = (gy & 1) * 2 + (xl & 1);
                        out[(((size_t)z * 24 + yy) * 32 + xx) * 384 + pp * 96 + oc] = bv;
                    } else {
                        out[(((size_t)z * 48 + 2 * gy + OQY) * 64 + 2 * xl + OQX) * 32 + oc] = bv;
                    }
                }
            }
        }
    }
}

// ---------------------------------------------------------------------------
// conv5: 3x3, 32->1, no ReLU. in NHWC bf16 (cnt,48,64,32) -> cost fp32
// ---------------------------------------------------------------------------
__global__ __launch_bounds__(256) void conv5_k(const bf16* __restrict__ in_,
                                               const float* __restrict__ w5,
                                               const float* __restrict__ b5,
                                               float* __restrict__ cost, int bd0, int cnt) {
    __shared__ float s_w5[9][32];
    const int tid = threadIdx.x;
    for (int i = tid; i < 288; i += 256) {
        int ic = i % 32, t = i / 32;
        s_w5[t][ic] = w5[ic * 9 + t];
    }
    __syncthreads();
    int idx = blockIdx.x * 256 + tid;
    if (idx >= cnt * 3072) return;
    int p = idx % 3072, z = idx / 3072;
    int y = p >> 6, x = p & 63;
    const unsigned short* in = (const unsigned short*)in_;
    float acc = b5[0];
#pragma unroll
    for (int ky = 0; ky < 3; ++ky) {
        int gy = y + ky - 1;
        if (gy < 0 || gy >= 48) continue;
#pragma unroll
        for (int kx = 0; kx < 3; ++kx) {
            int gx = x + kx - 1;
            if (gx < 0 || gx >= 64) continue;
            const ushort4* src = (const ushort4*)(in + ((size_t)(z * 48 + gy) * 64 + gx) * 32);
            const float* wr = s_w5[ky * 3 + kx];
#pragma unroll
            for (int e = 0; e < 8; ++e) {
                ushort4 u = src[e];
                acc = fmaf(us2f(u.x), wr[e * 4 + 0], acc);
                acc = fmaf(us2f(u.y), wr[e * 4 + 1], acc);
                acc = fmaf(us2f(u.z), wr[e * 4 + 2], acc);
                acc = fmaf(us2f(u.w), wr[e * 4 + 3], acc);
            }
        }
    }
    cost[(size_t)(bd0 + z) * 3072 + p] = acc;
}

// ---------------------------------------------------------------------------
// DAP (49x49) + softmax + flow expectation + coords. out fp32 (2,2,48,64)
// ---------------------------------------------------------------------------
__global__ __launch_bounds__(256) void dap_flow(const float* __restrict__ cost,
                                                const float* __restrict__ wdap,
                                                const float* __restrict__ coords,
                                                float* __restrict__ outp) {
    __shared__ float s_w[49 * 49];
    int tid = threadIdx.x;
    for (int i = tid; i < 2401; i += 256) s_w[i] = wdap[i];
    __syncthreads();
    int idx = blockIdx.x * 256 + tid;
    if (idx >= 2 * 3072) return;
    int p = idx % 3072, b = idx / 3072;
    float c[49];
#pragma unroll
    for (int d = 0; d < 49; ++d) c[d] = cost[((size_t)(b * 49 + d)) * 3072 + p];
    float mx = -1e30f;
    for (int e = 0; e < 49; ++e) {
        float s = 0.f;
#pragma unroll
        for (int d = 0; d < 49; ++d) s = fmaf(s_w[e * 49 + d], c[d], s);
        mx = fmaxf(mx, s);
    }
    float sum = 0.f, sx = 0.f, sy = 0.f;
    for (int e = 0; e < 49; ++e) {
        float s = 0.f;
#pragma unroll
        for (int d = 0; d < 49; ++d) s = fmaf(s_w[e * 49 + d], c[d], s);
        float pr = __expf(s - mx);
        sum += pr;
        sx += pr * (float)(e % 7 - 3);
        sy += pr * (float)(e / 7 - 3);
    }
    float inv = 1.f / sum;
    outp[(size_t)(b * 2 + 0) * 3072 + p] = coords[(size_t)(b * 2 + 0) * 3072 + p] + sx * inv;
    outp[(size_t)(b * 2 + 1) * 3072 + p] = coords[(size_t)(b * 2 + 1) * 3072 + p] + sy * inv;
}

// ---------------------------------------------------------------------------
extern "C" void kernel_launch(void* const* d_in, const int* in_sizes, int n_in,
                              void* d_out, int out_size, void* d_ws, size_t ws_size,
                              hipStream_t stream) {
    (void)in_sizes; (void)n_in;
    const float* feat1 = (const float*)d_in[0];
    const float* feat2 = (const float*)d_in[1];
    const float* coords = (const float*)d_in[2];
    const float* w0 = (const float*)d_in[3];
    const float* b0 = (const float*)d_in[4];
    const float* w1 = (const float*)d_in[5];
    const float* b1 = (const float*)d_in[6];
    const float* w2 = (const float*)d_in[7];
    const float* b2 = (const float*)d_in[8];
    const float* w3 = (const float*)d_in[9];
    const float* b3 = (const float*)d_in[10];
    const float* wd = (const float*)d_in[11];
    const float* bdc = (const float*)d_in[12];
    const float* w5 = (const float*)d_in[13];
    const float* b5 = (const float*)d_in[14];
    const float* wdap = (const float*)d_in[15];
    float* outp = (float*)d_out;

    // workspace layout (fixed):
    //  wp0 @0 (110592) | wp0a @110592 (110592) | wp1 @221184 (393216)
    //  wp2 @614400 (294912) | wp3 @909312 (147456) | wpd @1056768 (65536)
    //  f1n @1122304 (786432) | part0 @1908736 (2359296) | cost @4268032 (1204224)
    //  f2n @5472256 (786432) | fixed_end = 6258688
    char* ws = (char*)d_ws;
    bf16* wp0 = (bf16*)(ws + 0);
    bf16* wp0a = (bf16*)(ws + 110592);
    bf16* wp1 = (bf16*)(ws + 221184);
    bf16* wp2 = (bf16*)(ws + 614400);
    bf16* wp3 = (bf16*)(ws + 909312);
    bf16* wpd = (bf16*)(ws + 1056768);
    bf16* f1n = (bf16*)(ws + 1122304);
    float* part0 = (float*)(ws + 1908736);
    float* cost = (float*)(ws + 4268032);
    bf16* f2n = (bf16*)(ws + 5472256);
    const size_t fixed_end = 6258688;

    const int cand[7] = {98, 49, 25, 14, 7, 2, 1};
    int nb = 0;
    for (int i = 0; i < 7; ++i) {
        if (fixed_end + (size_t)983040 * cand[i] <= ws_size) { nb = cand[i]; break; }
    }
    if (nb == 0) {
        float val = 10000.f + (float)(ws_size >> 20);
        sentinel_k<<<dim3((out_size + 255) / 256), 256, 0, stream>>>(outp, out_size, val);
        return;
    }
    char* regA = ws + fixed_end;
    char* regB = regA + (size_t)393216 * nb;
    bf16* f2w = (bf16*)regA;  // (nb,48,64,64)
    bf16* x1 = (bf16*)regA;   // (nb,24,32,128)
    bf16* x3 = (bf16*)regA;   // (nb,24,32,64)
    bf16* x0p = (bf16*)regB;  // (nb,24,32,384) parity-packed
    bf16* x2 = (bf16*)regB;   // (nb,24,32,128)
    bf16* xd = (bf16*)regB;   // (nb,48,64,32)

    // packing + transposes + part0 (once per call)
    pack_w0<<<dim3(216), 256, 0, stream>>>(w0, wp0, 64);
    pack_w0<<<dim3(216), 256, 0, stream>>>(w0, wp0a, 0);
    pack_w1<<<dim3(768), 256, 0, stream>>>(w1, wp1);
    pack_simple<<<dim3(576), 256, 0, stream>>>(w2, wp2, 128, 128, 9);
    pack_simple<<<dim3(288), 256, 0, stream>>>(w3, wp3, 64, 128, 9);
    pack_wd<<<dim3(128), 256, 0, stream>>>(wd, wpd);
    to_nhwc<<<dim3(1536), 256, 0, stream>>>(feat1, f1n);
    to_nhwc<<<dim3(1536), 256, 0, stream>>>(feat2, f2n);
    // part0 = conv3x3(f1n, w0[:,:64]) + b0 -> fp32 NHWC, no ReLU (MFMA, OMODE=3)
    conv_mfma<64, 96, 48, 64, 2, -1, 1, -1, 1, 0, 3, 0, 0>
        <<<dim3(24, 2), 256, 0, stream>>>(f1n, wp0a, b0, nullptr, (bf16*)part0, 0);

    for (int s = 0; s < 98; s += nb) {
        int cnt = (98 - s < nb) ? (98 - s) : nb;
        warp_kernel<<<dim3(cnt * 192), 256, 0, stream>>>(f2n, coords, f2w, s, cnt);
        // conv0: IC=64 taps3x3 OC=96, base=part0, out parity-packed
        conv_mfma<64, 96, 48, 64, 2, -1, 1, -1, 1, 1, 1, 0, 0>
            <<<dim3(24, cnt), 256, 0, stream>>>(f2w, wp0, nullptr, part0, x0p, s);
        // conv1: IC=384 taps{-1,0}^2 OC=128
        conv_mfma<384, 128, 24, 32, 4, -1, 0, -1, 0, 0, 0, 0, 0>
            <<<dim3(6, cnt), 256, 0, stream>>>(x0p, wp1, b1, nullptr, x1, s);
        // conv2: IC=128 taps3x3 OC=128
        conv_mfma<128, 128, 24, 32, 4, -1, 1, -1, 1, 0, 0, 0, 0>
            <<<dim3(6, cnt), 256, 0, stream>>>(x1, wp2, b2, nullptr, x2, s);
        // conv3: IC=128 taps3x3 OC=64
        conv_mfma<128, 64, 24, 32, 4, -1, 1, -1, 1, 0, 0, 0, 0>
            <<<dim3(6, cnt), 256, 0, stream>>>(x2, wp3, b3, nullptr, x3, s);
        // deconv: 4 parity classes, 2x2 taps each
        conv_mfma<64, 32, 24, 32, 4, -1, 0, -1, 0, 0, 2, 0, 0>
            <<<dim3(6, cnt), 256, 0, stream>>>(x3, wpd + 0 * 8192, bdc, nullptr, xd, s);
        conv_mfma<64, 32, 24, 32, 4, -1, 0, 0, 1, 0, 2, 0, 1>
            <<<dim3(6, cnt), 256, 0, stream>>>(x3, wpd + 1 * 8192, bdc, nullptr, xd, s);
        conv_mfma<64, 32, 24, 32, 4, 0, 1, -1, 0, 0, 2, 1, 0>
            <<<dim3(6, cnt), 256, 0, stream>>>(x3, wpd + 2 * 8192, bdc, nullptr, xd, s);
        conv_mfma<64, 32, 24, 32, 4, 0, 1, 0, 1, 0, 2, 1, 1>
            <<<dim3(6, cnt), 256, 0, stream>>>(x3, wpd + 3 * 8192, bdc, nullptr, xd, s);
        // conv5
        conv5_k<<<dim3(cnt * 12), 256, 0, stream>>>(xd, w5, b5, cost, s, cnt);
    }

    dap_flow<<<dim3(24), 256, 0, stream>>>(cost, wdap, coords, outp);
}